// Round 1
// baseline (13964.333 us; speedup 1.0000x reference)
//
#include <hip/hip_runtime.h>
#include <cstdint>
#include <cstddef>

// ---------------------------------------------------------------------------
// Problem constants
// ---------------------------------------------------------------------------
#define NB   32          // batch
#define NT   1000        // time steps
#define NF   513         // features
#define NH   256         // hidden
#define NG   768         // 3*NH gate rows
#define NM   (NB*NT)     // 32000 GEMM rows

#define XP_ELEMS  ((size_t)NM * NG)       // 24,576,000
#define H_ELEMS   ((size_t)NM * NH)       //  8,192,000
#define WQ_ELEMS  ((size_t)NG * NH)       //    196,608
#define OUT_HALF  ((size_t)NM * NF)       // 16,416,000

// ---------------------------------------------------------------------------
// Generic tiled fp32 GEMM:  C[M,N] = A[M,K] @ W[N,K]^T + bias[N]
// CONCAT=true: A is x [32][2][1000][513]; row r=(b*1000+t), feature k is
// concat(x[b,0,t,:], x[b,1,t,:]).
// ---------------------------------------------------------------------------
#define GEMM_BM 128
#define GEMM_BN 64
#define GEMM_BK 16

template<bool CONCAT>
__global__ __launch_bounds__(256) void gemm_bias_kernel(
    const float* __restrict__ A, const float* __restrict__ W,
    const float* __restrict__ bias, float* __restrict__ C,
    int M, int N, int K)
{
    __shared__ float As[GEMM_BK][GEMM_BM];   // k-major
    __shared__ float Bs[GEMM_BK][GEMM_BN];
    const int tid = threadIdx.x;
    const int bm = blockIdx.x * GEMM_BM;
    const int bn = blockIdx.y * GEMM_BN;
    const int mt = tid >> 4;      // 0..15
    const int nt = tid & 15;      // 0..15
    const int m0 = mt * 8;
    const int n0 = nt * 4;

    float acc[8][4];
    #pragma unroll
    for (int i = 0; i < 8; ++i)
        #pragma unroll
        for (int j = 0; j < 4; ++j) acc[i][j] = 0.f;

    const bool kvec = ((K & 3) == 0);   // float4 alignment of row starts

    for (int k0 = 0; k0 < K; k0 += GEMM_BK) {
        // ---- stage A tile (128 rows x 16 k) : 512 quads, 2 per thread ----
        #pragma unroll
        for (int i = 0; i < 2; ++i) {
            int qid = tid * 2 + i;
            int m   = qid >> 2;
            int kq  = (qid & 3) << 2;
            int gm  = bm + m;
            int gk  = k0 + kq;
            float v0 = 0.f, v1 = 0.f, v2 = 0.f, v3 = 0.f;
            if (gm < M) {
                if (!CONCAT) {
                    if (kvec && gk + 4 <= K) {
                        float4 v = *(const float4*)(A + (size_t)gm * K + gk);
                        v0 = v.x; v1 = v.y; v2 = v.z; v3 = v.w;
                    } else {
                        if (gk + 0 < K) v0 = A[(size_t)gm * K + gk + 0];
                        if (gk + 1 < K) v1 = A[(size_t)gm * K + gk + 1];
                        if (gk + 2 < K) v2 = A[(size_t)gm * K + gk + 2];
                        if (gk + 3 < K) v3 = A[(size_t)gm * K + gk + 3];
                    }
                } else {
                    int b = gm / NT;
                    int t = gm - b * NT;
                    float tmp[4];
                    #pragma unroll
                    for (int u = 0; u < 4; ++u) {
                        int f = gk + u;
                        float val = 0.f;
                        if (f < K) {
                            int ch = (f >= NF) ? 1 : 0;
                            int ff = f - ch * NF;
                            val = A[(((size_t)(b * 2 + ch)) * NT + t) * NF + ff];
                        }
                        tmp[u] = val;
                    }
                    v0 = tmp[0]; v1 = tmp[1]; v2 = tmp[2]; v3 = tmp[3];
                }
            }
            As[kq + 0][m] = v0; As[kq + 1][m] = v1;
            As[kq + 2][m] = v2; As[kq + 3][m] = v3;
        }
        // ---- stage B tile (64 n-rows x 16 k) : 256 quads, 1 per thread ----
        {
            int n  = tid >> 2;
            int kq = (tid & 3) << 2;
            int gn = bn + n;
            int gk = k0 + kq;
            float v0 = 0.f, v1 = 0.f, v2 = 0.f, v3 = 0.f;
            if (gn < N) {
                if (kvec && gk + 4 <= K) {
                    float4 v = *(const float4*)(W + (size_t)gn * K + gk);
                    v0 = v.x; v1 = v.y; v2 = v.z; v3 = v.w;
                } else {
                    if (gk + 0 < K) v0 = W[(size_t)gn * K + gk + 0];
                    if (gk + 1 < K) v1 = W[(size_t)gn * K + gk + 1];
                    if (gk + 2 < K) v2 = W[(size_t)gn * K + gk + 2];
                    if (gk + 3 < K) v3 = W[(size_t)gn * K + gk + 3];
                }
            }
            Bs[kq + 0][n] = v0; Bs[kq + 1][n] = v1;
            Bs[kq + 2][n] = v2; Bs[kq + 3][n] = v3;
        }
        __syncthreads();
        // ---- micro-kernel ----
        #pragma unroll
        for (int k = 0; k < GEMM_BK; ++k) {
            float a[8], bb[4];
            *(float4*)&a[0] = *(const float4*)&As[k][m0];
            *(float4*)&a[4] = *(const float4*)&As[k][m0 + 4];
            *(float4*)&bb[0] = *(const float4*)&Bs[k][n0];
            #pragma unroll
            for (int i = 0; i < 8; ++i)
                #pragma unroll
                for (int j = 0; j < 4; ++j)
                    acc[i][j] = fmaf(a[i], bb[j], acc[i][j]);
        }
        __syncthreads();
    }
    // ---- epilogue ----
    #pragma unroll
    for (int i = 0; i < 8; ++i) {
        int gm = bm + m0 + i;
        if (gm >= M) continue;
        #pragma unroll
        for (int j = 0; j < 4; ++j) {
            int gn = bn + n0 + j;
            if (gn < N) C[(size_t)gm * N + gn] = acc[i][j] + bias[gn];
        }
    }
}

// ---------------------------------------------------------------------------
// Pack whh [768][256] into wq layout: wq4[kg*768 + row] = whh[row][4kg..4kg+3]
// -> coalesced float4 weight loads in the recurrence (thread j owns row j).
// ---------------------------------------------------------------------------
__global__ __launch_bounds__(256) void pack_whh_kernel(
    const float* __restrict__ whh, float* __restrict__ wq)
{
    int idx = blockIdx.x * 256 + threadIdx.x;   // over 768*256
    int row = idx >> 8;
    int k   = idx & 255;
    wq[((size_t)(k >> 2) * NG + row) * 4 + (k & 3)] = whh[idx];
}

// ---------------------------------------------------------------------------
// GRU recurrence. One workgroup per batch element (independent recurrences,
// no grid sync). 768 threads: thread j computes gate row j of hp = whh@h+bhh.
// Double-buffered h in LDS; hp staged through LDS for the gate recombine.
// Two parameter sets so real/imag GRUs run concurrently in one launch.
// ---------------------------------------------------------------------------
__global__ __launch_bounds__(768) void gru_rec_kernel(
    const float* __restrict__ xpA, const float* __restrict__ wqA,
    const float* __restrict__ bhhA, float* __restrict__ outA,
    const float* __restrict__ xpB, const float* __restrict__ wqB,
    const float* __restrict__ bhhB, float* __restrict__ outB,
    int nBatch)
{
    const int wg = blockIdx.x;
    const float* xp;  const float* wq;  const float* bhh;  float* out;  int b;
    if (wg < nBatch) { xp = xpA; wq = wqA; bhh = bhhA; out = outA; b = wg; }
    else             { xp = xpB; wq = wqB; bhh = bhhB; out = outB; b = wg - nBatch; }

    __shared__ float hbuf[2][NH];
    __shared__ float hp[NG];

    const int j = threadIdx.x;          // 0..767
    const float bj = bhh[j];
    if (j < NH) hbuf[0][j] = 0.f;
    __syncthreads();

    const float4* wrow = (const float4*)wq + j;   // wq4[kg*768 + j]

    for (int t = 0; t < NT; ++t) {
        const int cur = t & 1, nxt = cur ^ 1;
        // issue xp loads early so HBM latency hides under the dot loop
        float xr = 0.f, xz = 0.f, xn = 0.f, hprev = 0.f;
        if (j < NH) {
            size_t base = ((size_t)b * NT + t) * NG;
            xr = xp[base + j];
            xz = xp[base + NH + j];
            xn = xp[base + 2 * NH + j];
            hprev = hbuf[cur][j];
        }
        const float4* hv = (const float4*)hbuf[cur];
        float acc = 0.f;
        #pragma unroll 8
        for (int kg = 0; kg < NH / 4; ++kg) {
            float4 w  = wrow[(size_t)kg * NG];   // coalesced
            float4 h4 = hv[kg];                  // LDS broadcast
            acc += w.x * h4.x + w.y * h4.y + w.z * h4.z + w.w * h4.w;
        }
        hp[j] = acc + bj;
        __syncthreads();
        if (j < NH) {
            float hr = hp[j], hz = hp[j + NH], hn = hp[j + 2 * NH];
            float r  = 1.f / (1.f + __expf(-(xr + hr)));
            float z  = 1.f / (1.f + __expf(-(xz + hz)));
            float nn = tanhf(xn + r * hn);
            float hnew = (1.f - z) * nn + z * hprev;
            hbuf[nxt][j] = hnew;
            out[((size_t)b * NT + t) * NH + j] = hnew;
        }
        __syncthreads();
    }
}

// ---------------------------------------------------------------------------
// Launch
// ---------------------------------------------------------------------------
extern "C" void kernel_launch(void* const* d_in, const int* in_sizes, int n_in,
                              void* d_out, int out_size, void* d_ws, size_t ws_size,
                              hipStream_t stream)
{
    const float* x      = (const float*)d_in[0];
    const float* ds_w   = (const float*)d_in[1];
    const float* ds_b   = (const float*)d_in[2];
    const float* g1_wih = (const float*)d_in[3];
    const float* g1_whh = (const float*)d_in[4];
    const float* g1_bih = (const float*)d_in[5];
    const float* g1_bhh = (const float*)d_in[6];
    const float* gr_wih = (const float*)d_in[7];
    const float* gr_whh = (const float*)d_in[8];
    const float* gr_bih = (const float*)d_in[9];
    const float* gr_bhh = (const float*)d_in[10];
    const float* gi_wih = (const float*)d_in[11];
    const float* gi_whh = (const float*)d_in[12];
    const float* gi_bih = (const float*)d_in[13];
    const float* gi_bhh = (const float*)d_in[14];
    const float* dr_w   = (const float*)d_in[15];
    const float* dr_b   = (const float*)d_in[16];
    const float* di_w   = (const float*)d_in[17];
    const float* di_b   = (const float*)d_in[18];

    float* out = (float*)d_out;
    float* ws  = (float*)d_ws;

    // workspace layout (element offsets)
    float* wq1 = ws;
    float* wqr = wq1 + WQ_ELEMS;
    float* wqi = wqr + WQ_ELEMS;
    float* xpA = wqi + WQ_ELEMS;

    const size_t need_conc = (3 * WQ_ELEMS + 2 * XP_ELEMS + 3 * H_ELEMS) * sizeof(float);
    const bool conc = ws_size >= need_conc;

    float *xpB, *so, *sg, *r1, *i1;
    if (conc) {
        xpB = xpA + XP_ELEMS;
        so  = xpB + XP_ELEMS;
        sg  = so + H_ELEMS;
        i1  = sg + H_ELEMS;
        r1  = so;            // shared_out consumed before real_1 written
    } else {
        xpB = xpA;           // sequential reuse
        so  = xpA + XP_ELEMS;
        sg  = so + H_ELEMS;
        r1  = so;
        i1  = so;
    }

    const dim3 blk(256);
    const dim3 gN256(NM / GEMM_BM, NH / GEMM_BN);              // 250 x 4
    const dim3 gN768(NM / GEMM_BM, NG / GEMM_BN);              // 250 x 12
    const dim3 gN513(NM / GEMM_BM, (NF + GEMM_BN - 1) / GEMM_BN); // 250 x 9

    // pack recurrent weights (every call: inputs restored before each launch)
    pack_whh_kernel<<<dim3(NG), blk, 0, stream>>>(g1_whh, wq1);
    pack_whh_kernel<<<dim3(NG), blk, 0, stream>>>(gr_whh, wqr);
    pack_whh_kernel<<<dim3(NG), blk, 0, stream>>>(gi_whh, wqi);

    // shared dense: concat(x) [32000,1026] @ ds_w^T + ds_b -> so [32000,256]
    gemm_bias_kernel<true><<<gN256, blk, 0, stream>>>(x, ds_w, ds_b, so, NM, NH, 2 * NF);
    // xproj for GRU1
    gemm_bias_kernel<false><<<gN768, blk, 0, stream>>>(so, g1_wih, g1_bih, xpA, NM, NG, NH);
    // GRU1 recurrence -> sg
    gru_rec_kernel<<<dim3(NB), dim3(NG), 0, stream>>>(
        xpA, wq1, g1_bhh, sg, xpA, wq1, g1_bhh, sg, NB);

    if (conc) {
        gemm_bias_kernel<false><<<gN768, blk, 0, stream>>>(sg, gr_wih, gr_bih, xpA, NM, NG, NH);
        gemm_bias_kernel<false><<<gN768, blk, 0, stream>>>(sg, gi_wih, gi_bih, xpB, NM, NG, NH);
        // real + imag recurrences concurrently (64 workgroups)
        gru_rec_kernel<<<dim3(2 * NB), dim3(NG), 0, stream>>>(
            xpA, wqr, gr_bhh, r1, xpB, wqi, gi_bhh, i1, NB);
        gemm_bias_kernel<false><<<gN513, blk, 0, stream>>>(r1, dr_w, dr_b, out, NM, NF, NH);
        gemm_bias_kernel<false><<<gN513, blk, 0, stream>>>(i1, di_w, di_b, out + OUT_HALF, NM, NF, NH);
    } else {
        gemm_bias_kernel<false><<<gN768, blk, 0, stream>>>(sg, gr_wih, gr_bih, xpA, NM, NG, NH);
        gru_rec_kernel<<<dim3(NB), dim3(NG), 0, stream>>>(
            xpA, wqr, gr_bhh, r1, xpA, wqr, gr_bhh, r1, NB);
        gemm_bias_kernel<false><<<gN513, blk, 0, stream>>>(r1, dr_w, dr_b, out, NM, NF, NH);
        gemm_bias_kernel<false><<<gN768, blk, 0, stream>>>(sg, gi_wih, gi_bih, xpA, NM, NG, NH);
        gru_rec_kernel<<<dim3(NB), dim3(NG), 0, stream>>>(
            xpA, wqi, gi_bhh, i1, xpA, wqi, gi_bhh, i1, NB);
        gemm_bias_kernel<false><<<gN513, blk, 0, stream>>>(i1, di_w, di_b, out + OUT_HALF, NM, NF, NH);
    }
}

// Round 2
// 8004.813 us; speedup vs baseline: 1.7445x; 1.7445x over previous
//
#include <hip/hip_runtime.h>
#include <cstdint>
#include <cstddef>

// ---------------------------------------------------------------------------
// Problem constants
// ---------------------------------------------------------------------------
#define NB   32          // batch
#define NT   1000        // time steps
#define NF   513         // features
#define NH   256         // hidden
#define NG   768         // 3*NH gate rows
#define NM   (NB*NT)     // 32000 GEMM rows

#define XP_ELEMS  ((size_t)NM * NG)       // 24,576,000
#define H_ELEMS   ((size_t)NM * NH)       //  8,192,000
#define WPK_ELEMS ((size_t)NG * NH / 2)   //  98,304 (f16x2 words)
#define OUT_HALF  ((size_t)NM * NF)       // 16,416,000

typedef _Float16 f16x2 __attribute__((ext_vector_type(2)));

static __device__ __forceinline__ f16x2 as_f16x2(float x) {
    return __builtin_bit_cast(f16x2, x);
}

#if __has_builtin(__builtin_amdgcn_fdot2)
static __device__ __forceinline__ float fdot2(f16x2 h, f16x2 w, float acc) {
    return __builtin_amdgcn_fdot2(h, w, acc, false);
}
#else
static __device__ __forceinline__ float fdot2(f16x2 h, f16x2 w, float acc) {
    return acc + (float)h.x * (float)w.x + (float)h.y * (float)w.y;
}
#endif

// ---------------------------------------------------------------------------
// Generic tiled fp32 GEMM:  C[M,N] = A[M,K] @ W[N,K]^T + bias[N]
// CONCAT=true: A is x [32][2][1000][513]; row r=(b*1000+t), feature k is
// concat(x[b,0,t,:], x[b,1,t,:]).
// ---------------------------------------------------------------------------
#define GEMM_BM 128
#define GEMM_BN 64
#define GEMM_BK 16

template<bool CONCAT>
__global__ __launch_bounds__(256) void gemm_bias_kernel(
    const float* __restrict__ A, const float* __restrict__ W,
    const float* __restrict__ bias, float* __restrict__ C,
    int M, int N, int K)
{
    __shared__ float As[GEMM_BK][GEMM_BM];   // k-major
    __shared__ float Bs[GEMM_BK][GEMM_BN];
    const int tid = threadIdx.x;
    const int bm = blockIdx.x * GEMM_BM;
    const int bn = blockIdx.y * GEMM_BN;
    const int mt = tid >> 4;      // 0..15
    const int nt = tid & 15;      // 0..15
    const int m0 = mt * 8;
    const int n0 = nt * 4;

    float acc[8][4];
    #pragma unroll
    for (int i = 0; i < 8; ++i)
        #pragma unroll
        for (int j = 0; j < 4; ++j) acc[i][j] = 0.f;

    const bool kvec = ((K & 3) == 0);   // float4 alignment of row starts

    for (int k0 = 0; k0 < K; k0 += GEMM_BK) {
        // ---- stage A tile (128 rows x 16 k) : 512 quads, 2 per thread ----
        #pragma unroll
        for (int i = 0; i < 2; ++i) {
            int qid = tid * 2 + i;
            int m   = qid >> 2;
            int kq  = (qid & 3) << 2;
            int gm  = bm + m;
            int gk  = k0 + kq;
            float v0 = 0.f, v1 = 0.f, v2 = 0.f, v3 = 0.f;
            if (gm < M) {
                if (!CONCAT) {
                    if (kvec && gk + 4 <= K) {
                        float4 v = *(const float4*)(A + (size_t)gm * K + gk);
                        v0 = v.x; v1 = v.y; v2 = v.z; v3 = v.w;
                    } else {
                        if (gk + 0 < K) v0 = A[(size_t)gm * K + gk + 0];
                        if (gk + 1 < K) v1 = A[(size_t)gm * K + gk + 1];
                        if (gk + 2 < K) v2 = A[(size_t)gm * K + gk + 2];
                        if (gk + 3 < K) v3 = A[(size_t)gm * K + gk + 3];
                    }
                } else {
                    int b = gm / NT;
                    int t = gm - b * NT;
                    float tmp[4];
                    #pragma unroll
                    for (int u = 0; u < 4; ++u) {
                        int f = gk + u;
                        float val = 0.f;
                        if (f < K) {
                            int ch = (f >= NF) ? 1 : 0;
                            int ff = f - ch * NF;
                            val = A[(((size_t)(b * 2 + ch)) * NT + t) * NF + ff];
                        }
                        tmp[u] = val;
                    }
                    v0 = tmp[0]; v1 = tmp[1]; v2 = tmp[2]; v3 = tmp[3];
                }
            }
            As[kq + 0][m] = v0; As[kq + 1][m] = v1;
            As[kq + 2][m] = v2; As[kq + 3][m] = v3;
        }
        // ---- stage B tile (64 n-rows x 16 k) : 256 quads, 1 per thread ----
        {
            int n  = tid >> 2;
            int kq = (tid & 3) << 2;
            int gn = bn + n;
            int gk = k0 + kq;
            float v0 = 0.f, v1 = 0.f, v2 = 0.f, v3 = 0.f;
            if (gn < N) {
                if (kvec && gk + 4 <= K) {
                    float4 v = *(const float4*)(W + (size_t)gn * K + gk);
                    v0 = v.x; v1 = v.y; v2 = v.z; v3 = v.w;
                } else {
                    if (gk + 0 < K) v0 = W[(size_t)gn * K + gk + 0];
                    if (gk + 1 < K) v1 = W[(size_t)gn * K + gk + 1];
                    if (gk + 2 < K) v2 = W[(size_t)gn * K + gk + 2];
                    if (gk + 3 < K) v3 = W[(size_t)gn * K + gk + 3];
                }
            }
            Bs[kq + 0][n] = v0; Bs[kq + 1][n] = v1;
            Bs[kq + 2][n] = v2; Bs[kq + 3][n] = v3;
        }
        __syncthreads();
        // ---- micro-kernel ----
        #pragma unroll
        for (int k = 0; k < GEMM_BK; ++k) {
            float a[8], bb[4];
            *(float4*)&a[0] = *(const float4*)&As[k][m0];
            *(float4*)&a[4] = *(const float4*)&As[k][m0 + 4];
            *(float4*)&bb[0] = *(const float4*)&Bs[k][n0];
            #pragma unroll
            for (int i = 0; i < 8; ++i)
                #pragma unroll
                for (int j = 0; j < 4; ++j)
                    acc[i][j] = fmaf(a[i], bb[j], acc[i][j]);
        }
        __syncthreads();
    }
    // ---- epilogue ----
    #pragma unroll
    for (int i = 0; i < 8; ++i) {
        int gm = bm + m0 + i;
        if (gm >= M) continue;
        #pragma unroll
        for (int j = 0; j < 4; ++j) {
            int gn = bn + n0 + j;
            if (gn < N) C[(size_t)gm * N + gn] = acc[i][j] + bias[gn];
        }
    }
}

// ---------------------------------------------------------------------------
// Pack whh [768][256] fp32 -> f16x2 words, layout wpk[k2*768 + row] so the
// recurrence prologue load (thread t reads rows t, 256+t, 512+t for each k2)
// is coalesced across threads.
// ---------------------------------------------------------------------------
__global__ __launch_bounds__(256) void pack_whh_f16(
    const float* __restrict__ whh, unsigned* __restrict__ wpk)
{
    int idx = blockIdx.x * 256 + threadIdx.x;   // over 768*128
    int k2  = idx / NG;
    int row = idx - k2 * NG;
    float lo = whh[row * NH + 2 * k2];
    float hi = whh[row * NH + 2 * k2 + 1];
    f16x2 w;
    w.x = (_Float16)lo;
    w.y = (_Float16)hi;
    wpk[idx] = __builtin_bit_cast(unsigned, w);
}

// ---------------------------------------------------------------------------
// GRU recurrence, register-resident f16 weights.
// One WG (256 threads = 4 waves) per batch element. Thread t owns gate rows
// {t, 256+t, 512+t} -> all three gate partials are thread-local, no hp
// exchange. Weights: 3 x 128 f16x2 VGPRs/thread (384 regs), loaded once.
// h staged in LDS as f16 (512 B) -> 32 ds_read_b128 per thread per step.
// Two parameter sets so real/imag GRUs run concurrently in one launch.
// ---------------------------------------------------------------------------
__global__ __launch_bounds__(256, 1) void gru_rec_kernel(
    const float* __restrict__ xpA, const unsigned* __restrict__ wpkA,
    const float* __restrict__ bhhA, float* __restrict__ outA,
    const float* __restrict__ xpB, const unsigned* __restrict__ wpkB,
    const float* __restrict__ bhhB, float* __restrict__ outB,
    int nBatch)
{
    const int wg = blockIdx.x;
    const float* xp;  const unsigned* wpk;  const float* bhh;  float* out;  int b;
    if (wg < nBatch) { xp = xpA; wpk = wpkA; bhh = bhhA; out = outA; b = wg; }
    else             { xp = xpB; wpk = wpkB; bhh = bhhB; out = outB; b = wg - nBatch; }

    const int tid = threadIdx.x;   // 0..255

    // ---- load weights into registers (once per 1000 steps) ----
    f16x2 w0[128], w1[128], w2[128];
    #pragma unroll
    for (int k2 = 0; k2 < 128; ++k2) {
        w0[k2] = __builtin_bit_cast(f16x2, wpk[(size_t)k2 * NG + tid]);
        w1[k2] = __builtin_bit_cast(f16x2, wpk[(size_t)k2 * NG + NH + tid]);
        w2[k2] = __builtin_bit_cast(f16x2, wpk[(size_t)k2 * NG + 2 * NH + tid]);
    }
    const float br = bhh[tid];
    const float bz = bhh[NH + tid];
    const float bn = bhh[2 * NH + tid];

    __shared__ __align__(16) _Float16 hbuf[NH];
    hbuf[tid] = (_Float16)0.f;
    float hreg = 0.f;
    __syncthreads();

    for (int t = 0; t < NT; ++t) {
        // issue xp loads early; consumed after the dot (HBM latency hidden)
        const size_t base = ((size_t)b * NT + t) * NG;
        const float xr = xp[base + tid];
        const float xz = xp[base + NH + tid];
        const float xn = xp[base + 2 * NH + tid];

        // ---- three 256-length dots, weights in regs, h broadcast from LDS
        float a0 = 0.f, a1 = 0.f, a2 = 0.f, a3 = 0.f;   // r gate
        float c0 = 0.f, c1 = 0.f, c2 = 0.f, c3 = 0.f;   // z gate
        float d0 = 0.f, d1 = 0.f, d2 = 0.f, d3 = 0.f;   // n gate
        const float4* h4 = (const float4*)hbuf;
        #pragma unroll
        for (int i = 0; i < 32; ++i) {
            float4 hb = h4[i];
            f16x2 h0 = as_f16x2(hb.x);
            f16x2 h1 = as_f16x2(hb.y);
            f16x2 h2 = as_f16x2(hb.z);
            f16x2 h3 = as_f16x2(hb.w);
            a0 = fdot2(h0, w0[4 * i + 0], a0);
            a1 = fdot2(h1, w0[4 * i + 1], a1);
            a2 = fdot2(h2, w0[4 * i + 2], a2);
            a3 = fdot2(h3, w0[4 * i + 3], a3);
            c0 = fdot2(h0, w1[4 * i + 0], c0);
            c1 = fdot2(h1, w1[4 * i + 1], c1);
            c2 = fdot2(h2, w1[4 * i + 2], c2);
            c3 = fdot2(h3, w1[4 * i + 3], c3);
            d0 = fdot2(h0, w2[4 * i + 0], d0);
            d1 = fdot2(h1, w2[4 * i + 1], d1);
            d2 = fdot2(h2, w2[4 * i + 2], d2);
            d3 = fdot2(h3, w2[4 * i + 3], d3);
        }
        const float hr = (a0 + a1) + (a2 + a3) + br;
        const float hz = (c0 + c1) + (c2 + c3) + bz;
        const float hn = (d0 + d1) + (d2 + d3) + bn;

        __syncthreads();   // all dots done reading hbuf

        const float r    = 1.f / (1.f + __expf(-(xr + hr)));
        const float z    = 1.f / (1.f + __expf(-(xz + hz)));
        const float pre  = xn + r * hn;
        const float e2   = __expf(2.f * pre);
        const float n    = 1.f - 2.f / (e2 + 1.f);      // tanh(pre)
        const float hnew = (1.f - z) * n + z * hreg;
        hreg = hnew;
        hbuf[tid] = (_Float16)hnew;
        out[((size_t)b * NT + t) * NH + tid] = hnew;

        __syncthreads();   // new h visible before next step's dots
    }
}

// ---------------------------------------------------------------------------
// Launch
// ---------------------------------------------------------------------------
extern "C" void kernel_launch(void* const* d_in, const int* in_sizes, int n_in,
                              void* d_out, int out_size, void* d_ws, size_t ws_size,
                              hipStream_t stream)
{
    const float* x      = (const float*)d_in[0];
    const float* ds_w   = (const float*)d_in[1];
    const float* ds_b   = (const float*)d_in[2];
    const float* g1_wih = (const float*)d_in[3];
    const float* g1_whh = (const float*)d_in[4];
    const float* g1_bih = (const float*)d_in[5];
    const float* g1_bhh = (const float*)d_in[6];
    const float* gr_wih = (const float*)d_in[7];
    const float* gr_whh = (const float*)d_in[8];
    const float* gr_bih = (const float*)d_in[9];
    const float* gr_bhh = (const float*)d_in[10];
    const float* gi_wih = (const float*)d_in[11];
    const float* gi_whh = (const float*)d_in[12];
    const float* gi_bih = (const float*)d_in[13];
    const float* gi_bhh = (const float*)d_in[14];
    const float* dr_w   = (const float*)d_in[15];
    const float* dr_b   = (const float*)d_in[16];
    const float* di_w   = (const float*)d_in[17];
    const float* di_b   = (const float*)d_in[18];

    float* out = (float*)d_out;
    float* ws  = (float*)d_ws;

    // workspace layout (float-element offsets)
    unsigned* wpk1 = (unsigned*)ws;
    unsigned* wpkr = wpk1 + WPK_ELEMS;
    unsigned* wpki = wpkr + WPK_ELEMS;
    float* xpA = ws + 3 * WPK_ELEMS;

    const size_t need_conc = (3 * WPK_ELEMS + 2 * XP_ELEMS + 3 * H_ELEMS) * sizeof(float);
    const bool conc = ws_size >= need_conc;

    float *xpB, *so, *sg, *r1, *i1;
    if (conc) {
        xpB = xpA + XP_ELEMS;
        so  = xpB + XP_ELEMS;
        sg  = so + H_ELEMS;
        i1  = sg + H_ELEMS;
        r1  = so;            // shared_out consumed before real_1 written
    } else {
        xpB = xpA;           // sequential reuse
        so  = xpA + XP_ELEMS;
        sg  = so + H_ELEMS;
        r1  = so;
        i1  = so;
    }

    const dim3 blk(256);
    const dim3 gN256(NM / GEMM_BM, NH / GEMM_BN);                 // 250 x 4
    const dim3 gN768(NM / GEMM_BM, NG / GEMM_BN);                 // 250 x 12
    const dim3 gN513(NM / GEMM_BM, (NF + GEMM_BN - 1) / GEMM_BN); // 250 x 9
    const dim3 gPack((NG * NH / 2) / 256);                        // 384

    // pack recurrent weights to f16 (every call)
    pack_whh_f16<<<gPack, blk, 0, stream>>>(g1_whh, wpk1);
    pack_whh_f16<<<gPack, blk, 0, stream>>>(gr_whh, wpkr);
    pack_whh_f16<<<gPack, blk, 0, stream>>>(gi_whh, wpki);

    // shared dense: concat(x) [32000,1026] @ ds_w^T + ds_b -> so [32000,256]
    gemm_bias_kernel<true><<<gN256, blk, 0, stream>>>(x, ds_w, ds_b, so, NM, NH, 2 * NF);
    // xproj for GRU1
    gemm_bias_kernel<false><<<gN768, blk, 0, stream>>>(so, g1_wih, g1_bih, xpA, NM, NG, NH);
    // GRU1 recurrence -> sg
    gru_rec_kernel<<<dim3(NB), blk, 0, stream>>>(
        xpA, wpk1, g1_bhh, sg, xpA, wpk1, g1_bhh, sg, NB);

    if (conc) {
        gemm_bias_kernel<false><<<gN768, blk, 0, stream>>>(sg, gr_wih, gr_bih, xpA, NM, NG, NH);
        gemm_bias_kernel<false><<<gN768, blk, 0, stream>>>(sg, gi_wih, gi_bih, xpB, NM, NG, NH);
        // real + imag recurrences concurrently (64 workgroups)
        gru_rec_kernel<<<dim3(2 * NB), blk, 0, stream>>>(
            xpA, wpkr, gr_bhh, r1, xpB, wpki, gi_bhh, i1, NB);
        gemm_bias_kernel<false><<<gN513, blk, 0, stream>>>(r1, dr_w, dr_b, out, NM, NF, NH);
        gemm_bias_kernel<false><<<gN513, blk, 0, stream>>>(i1, di_w, di_b, out + OUT_HALF, NM, NF, NH);
    } else {
        gemm_bias_kernel<false><<<gN768, blk, 0, stream>>>(sg, gr_wih, gr_bih, xpA, NM, NG, NH);
        gru_rec_kernel<<<dim3(NB), blk, 0, stream>>>(
            xpA, wpkr, gr_bhh, r1, xpA, wpkr, gr_bhh, r1, NB);
        gemm_bias_kernel<false><<<gN513, blk, 0, stream>>>(r1, dr_w, dr_b, out, NM, NF, NH);
        gemm_bias_kernel<false><<<gN768, blk, 0, stream>>>(sg, gi_wih, gi_bih, xpA, NM, NG, NH);
        gru_rec_kernel<<<dim3(NB), blk, 0, stream>>>(
            xpA, wpki, gi_bhh, i1, xpA, wpki, gi_bhh, i1, NB);
        gemm_bias_kernel<false><<<gN513, blk, 0, stream>>>(i1, di_w, di_b, out + OUT_HALF, NM, NF, NH);
    }
}

// Round 3
// 3686.099 us; speedup vs baseline: 3.7884x; 2.1716x over previous
//
#include <hip/hip_runtime.h>
#include <cstdint>
#include <cstddef>

// ---------------------------------------------------------------------------
// Problem constants
// ---------------------------------------------------------------------------
#define NB   32          // batch
#define NT   1000        // time steps
#define NF   513         // features
#define NH   256         // hidden
#define NG   768         // 3*NH gate rows
#define NM   (NB*NT)     // 32000 GEMM rows

#define XP_ELEMS  ((size_t)NM * NG)       // 24,576,000
#define H_ELEMS   ((size_t)NM * NH)       //  8,192,000
#define WPK_ELEMS ((size_t)NG * NH / 2)   //  98,304 (f16x2 words)
#define OUT_HALF  ((size_t)NM * NF)       // 16,416,000

typedef _Float16 f16x2 __attribute__((ext_vector_type(2)));

static __device__ __forceinline__ f16x2 as_f16x2(float x) {
    return __builtin_bit_cast(f16x2, x);
}
static __device__ __forceinline__ f16x2 as_f16x2u(unsigned x) {
    return __builtin_bit_cast(f16x2, x);
}

#if __has_builtin(__builtin_amdgcn_fdot2)
static __device__ __forceinline__ float fdot2(f16x2 h, f16x2 w, float acc) {
    return __builtin_amdgcn_fdot2(h, w, acc, false);
}
#else
static __device__ __forceinline__ float fdot2(f16x2 h, f16x2 w, float acc) {
    return acc + (float)h.x * (float)w.x + (float)h.y * (float)w.y;
}
#endif

// ---------------------------------------------------------------------------
// Generic tiled fp32 GEMM:  C[M,N] = A[M,K] @ W[N,K]^T + bias[N]
// CONCAT=true: A is x [32][2][1000][513]; row r=(b*1000+t), feature k is
// concat(x[b,0,t,:], x[b,1,t,:]).
// ---------------------------------------------------------------------------
#define GEMM_BM 128
#define GEMM_BN 64
#define GEMM_BK 16

template<bool CONCAT>
__global__ __launch_bounds__(256) void gemm_bias_kernel(
    const float* __restrict__ A, const float* __restrict__ W,
    const float* __restrict__ bias, float* __restrict__ C,
    int M, int N, int K)
{
    __shared__ float As[GEMM_BK][GEMM_BM];   // k-major
    __shared__ float Bs[GEMM_BK][GEMM_BN];
    const int tid = threadIdx.x;
    const int bm = blockIdx.x * GEMM_BM;
    const int bn = blockIdx.y * GEMM_BN;
    const int mt = tid >> 4;      // 0..15
    const int nt = tid & 15;      // 0..15
    const int m0 = mt * 8;
    const int n0 = nt * 4;

    float acc[8][4];
    #pragma unroll
    for (int i = 0; i < 8; ++i)
        #pragma unroll
        for (int j = 0; j < 4; ++j) acc[i][j] = 0.f;

    const bool kvec = ((K & 3) == 0);   // float4 alignment of row starts

    for (int k0 = 0; k0 < K; k0 += GEMM_BK) {
        // ---- stage A tile (128 rows x 16 k) : 512 quads, 2 per thread ----
        #pragma unroll
        for (int i = 0; i < 2; ++i) {
            int qid = tid * 2 + i;
            int m   = qid >> 2;
            int kq  = (qid & 3) << 2;
            int gm  = bm + m;
            int gk  = k0 + kq;
            float v0 = 0.f, v1 = 0.f, v2 = 0.f, v3 = 0.f;
            if (gm < M) {
                if (!CONCAT) {
                    if (kvec && gk + 4 <= K) {
                        float4 v = *(const float4*)(A + (size_t)gm * K + gk);
                        v0 = v.x; v1 = v.y; v2 = v.z; v3 = v.w;
                    } else {
                        if (gk + 0 < K) v0 = A[(size_t)gm * K + gk + 0];
                        if (gk + 1 < K) v1 = A[(size_t)gm * K + gk + 1];
                        if (gk + 2 < K) v2 = A[(size_t)gm * K + gk + 2];
                        if (gk + 3 < K) v3 = A[(size_t)gm * K + gk + 3];
                    }
                } else {
                    int b = gm / NT;
                    int t = gm - b * NT;
                    float tmp[4];
                    #pragma unroll
                    for (int u = 0; u < 4; ++u) {
                        int f = gk + u;
                        float val = 0.f;
                        if (f < K) {
                            int ch = (f >= NF) ? 1 : 0;
                            int ff = f - ch * NF;
                            val = A[(((size_t)(b * 2 + ch)) * NT + t) * NF + ff];
                        }
                        tmp[u] = val;
                    }
                    v0 = tmp[0]; v1 = tmp[1]; v2 = tmp[2]; v3 = tmp[3];
                }
            }
            As[kq + 0][m] = v0; As[kq + 1][m] = v1;
            As[kq + 2][m] = v2; As[kq + 3][m] = v3;
        }
        // ---- stage B tile (64 n-rows x 16 k) : 256 quads, 1 per thread ----
        {
            int n  = tid >> 2;
            int kq = (tid & 3) << 2;
            int gn = bn + n;
            int gk = k0 + kq;
            float v0 = 0.f, v1 = 0.f, v2 = 0.f, v3 = 0.f;
            if (gn < N) {
                if (kvec && gk + 4 <= K) {
                    float4 v = *(const float4*)(W + (size_t)gn * K + gk);
                    v0 = v.x; v1 = v.y; v2 = v.z; v3 = v.w;
                } else {
                    if (gk + 0 < K) v0 = W[(size_t)gn * K + gk + 0];
                    if (gk + 1 < K) v1 = W[(size_t)gn * K + gk + 1];
                    if (gk + 2 < K) v2 = W[(size_t)gn * K + gk + 2];
                    if (gk + 3 < K) v3 = W[(size_t)gn * K + gk + 3];
                }
            }
            Bs[kq + 0][n] = v0; Bs[kq + 1][n] = v1;
            Bs[kq + 2][n] = v2; Bs[kq + 3][n] = v3;
        }
        __syncthreads();
        // ---- micro-kernel ----
        #pragma unroll
        for (int k = 0; k < GEMM_BK; ++k) {
            float a[8], bb[4];
            *(float4*)&a[0] = *(const float4*)&As[k][m0];
            *(float4*)&a[4] = *(const float4*)&As[k][m0 + 4];
            *(float4*)&bb[0] = *(const float4*)&Bs[k][n0];
            #pragma unroll
            for (int i = 0; i < 8; ++i)
                #pragma unroll
                for (int j = 0; j < 4; ++j)
                    acc[i][j] = fmaf(a[i], bb[j], acc[i][j]);
        }
        __syncthreads();
    }
    // ---- epilogue ----
    #pragma unroll
    for (int i = 0; i < 8; ++i) {
        int gm = bm + m0 + i;
        if (gm >= M) continue;
        #pragma unroll
        for (int j = 0; j < 4; ++j) {
            int gn = bn + n0 + j;
            if (gn < N) C[(size_t)gm * N + gn] = acc[i][j] + bias[gn];
        }
    }
}

// ---------------------------------------------------------------------------
// Pack whh [768][256] fp32 -> f16x2 words in uint4-friendly layout:
//   wq[((k2>>2)*NG + row)*4 + (k2&3)]   (k2 = column pair index, 0..127)
// so a thread's prologue load of 4 consecutive k2 for one row is one uint4,
// coalesced across rows.
// ---------------------------------------------------------------------------
__global__ __launch_bounds__(256) void pack_whh_f16(
    const float* __restrict__ whh, unsigned* __restrict__ wpk)
{
    int idx = blockIdx.x * 256 + threadIdx.x;   // over 768*128
    int k2  = idx / NG;                         // 0..127
    int row = idx - k2 * NG;                    // 0..767
    float lo = whh[row * NH + 2 * k2];
    float hi = whh[row * NH + 2 * k2 + 1];
    f16x2 w;
    w.x = (_Float16)lo;
    w.y = (_Float16)hi;
    wpk[((size_t)(k2 >> 2) * NG + row) * 4 + (k2 & 3)] = __builtin_bit_cast(unsigned, w);
}

// ---------------------------------------------------------------------------
// GRU recurrence, register-resident f16 weights, 2-way k-split.
// One WG (512 threads = 8 waves) per batch element. Thread (u, ph):
//   u = tid&255 (hidden unit), ph = tid>>8 (k-half).
// Owns gate rows {u, u+256, u+512} for k in [128*ph, 128*ph+128):
//   3 x 32 uint (f16x2) weight VGPRs = 96 regs -> allocator can keep resident
//   (round-2's 384-reg version was rematerialized from L2 every step).
// h lives in LDS as f16; all lanes read the same address -> broadcast.
// Partial gate sums combined via 3KB LDS buffer; gate math on ph==0 only.
// Two parameter sets so real/imag GRUs run concurrently in one launch.
// ---------------------------------------------------------------------------
__global__ __launch_bounds__(512, 2) void gru_rec_kernel(
    const float* __restrict__ xpA, const unsigned* __restrict__ wpkA,
    const float* __restrict__ bhhA, float* __restrict__ outA,
    const float* __restrict__ xpB, const unsigned* __restrict__ wpkB,
    const float* __restrict__ bhhB, float* __restrict__ outB,
    int nBatch)
{
    const int wg = blockIdx.x;
    const float* xp;  const unsigned* wpk;  const float* bhh;  float* out;  int b;
    if (wg < nBatch) { xp = xpA; wpk = wpkA; bhh = bhhA; out = outA; b = wg; }
    else             { xp = xpB; wpk = wpkB; bhh = bhhB; out = outB; b = wg - nBatch; }

    const int tid = threadIdx.x;       // 0..511
    const int u   = tid & (NH - 1);    // hidden unit
    const int ph  = tid >> 8;          // k-half: 0 or 1

    // ---- load this thread's weight slice into registers (once) ----
    // k2 range: [64*ph, 64*ph+64) in groups of 4 -> 16 uint4 per gate.
    unsigned w0[64], w1[64], w2[64];
    {
        const uint4* wq4 = (const uint4*)wpk;
        #pragma unroll
        for (int i = 0; i < 16; ++i) {
            const int k2g = ph * 16 + i;
            uint4 a = wq4[(size_t)k2g * NG + u];
            uint4 c = wq4[(size_t)k2g * NG + NH + u];
            uint4 d = wq4[(size_t)k2g * NG + 2 * NH + u];
            w0[4*i+0] = a.x; w0[4*i+1] = a.y; w0[4*i+2] = a.z; w0[4*i+3] = a.w;
            w1[4*i+0] = c.x; w1[4*i+1] = c.y; w1[4*i+2] = c.z; w1[4*i+3] = c.w;
            w2[4*i+0] = d.x; w2[4*i+1] = d.y; w2[4*i+2] = d.z; w2[4*i+3] = d.w;
        }
    }
    float br = 0.f, bz = 0.f, bn = 0.f;
    if (!ph) { br = bhh[u]; bz = bhh[NH + u]; bn = bhh[2 * NH + u]; }

    __shared__ __align__(16) _Float16 hbuf[NH];
    __shared__ float part[3][NH];
    if (tid < NH) hbuf[tid] = (_Float16)0.f;
    float hreg = 0.f;
    __syncthreads();

    // preload xp for t=0 (ph==0 threads only)
    float xr = 0.f, xz = 0.f, xn = 0.f;
    if (!ph) {
        const size_t base = (size_t)b * NT * NG + u;
        xr = xp[base];
        xz = xp[base + NH];
        xn = xp[base + 2 * NH];
    }

    for (int t = 0; t < NT; ++t) {
        // prefetch next step's xp while this step's dot runs
        float pxr = 0.f, pxz = 0.f, pxn = 0.f;
        if (!ph) {
            const int tn = (t + 1 < NT) ? (t + 1) : t;
            const size_t base = ((size_t)b * NT + tn) * NG + u;
            pxr = xp[base];
            pxz = xp[base + NH];
            pxn = xp[base + 2 * NH];
        }

        // ---- three 128-length dots over this thread's k-half ----
        const float4* h4 = (const float4*)hbuf + ph * 16;
        float a0 = 0.f, a1 = 0.f, c0 = 0.f, c1 = 0.f, d0 = 0.f, d1 = 0.f;
        #pragma unroll
        for (int i = 0; i < 16; ++i) {
            float4 hb = h4[i];                 // same addr across wave: broadcast
            f16x2 h0 = as_f16x2(hb.x);
            f16x2 h1 = as_f16x2(hb.y);
            f16x2 h2 = as_f16x2(hb.z);
            f16x2 h3 = as_f16x2(hb.w);
            a0 = fdot2(h0, as_f16x2u(w0[4*i+0]), a0);
            a1 = fdot2(h1, as_f16x2u(w0[4*i+1]), a1);
            a0 = fdot2(h2, as_f16x2u(w0[4*i+2]), a0);
            a1 = fdot2(h3, as_f16x2u(w0[4*i+3]), a1);
            c0 = fdot2(h0, as_f16x2u(w1[4*i+0]), c0);
            c1 = fdot2(h1, as_f16x2u(w1[4*i+1]), c1);
            c0 = fdot2(h2, as_f16x2u(w1[4*i+2]), c0);
            c1 = fdot2(h3, as_f16x2u(w1[4*i+3]), c1);
            d0 = fdot2(h0, as_f16x2u(w2[4*i+0]), d0);
            d1 = fdot2(h1, as_f16x2u(w2[4*i+1]), d1);
            d0 = fdot2(h2, as_f16x2u(w2[4*i+2]), d0);
            d1 = fdot2(h3, as_f16x2u(w2[4*i+3]), d1);
        }
        const float sr = a0 + a1;
        const float sz = c0 + c1;
        const float sn = d0 + d1;

        if (ph) { part[0][u] = sr; part[1][u] = sz; part[2][u] = sn; }
        __syncthreads();   // dots done reading hbuf; partials visible

        if (!ph) {
            const float hr = sr + part[0][u] + br;
            const float hz = sz + part[1][u] + bz;
            const float hn = sn + part[2][u] + bn;
            const float r    = 1.f / (1.f + __expf(-(xr + hr)));
            const float z    = 1.f / (1.f + __expf(-(xz + hz)));
            const float pre  = xn + r * hn;
            const float e2   = __expf(2.f * pre);
            const float n    = 1.f - 2.f / (e2 + 1.f);      // tanh(pre)
            const float hnew = (1.f - z) * n + z * hreg;
            hreg = hnew;
            hbuf[u] = (_Float16)hnew;
            out[((size_t)b * NT + t) * NH + u] = hnew;
        }
        __syncthreads();   // new h visible before next step's dots

        xr = pxr; xz = pxz; xn = pxn;
    }
}

// ---------------------------------------------------------------------------
// Launch
// ---------------------------------------------------------------------------
extern "C" void kernel_launch(void* const* d_in, const int* in_sizes, int n_in,
                              void* d_out, int out_size, void* d_ws, size_t ws_size,
                              hipStream_t stream)
{
    const float* x      = (const float*)d_in[0];
    const float* ds_w   = (const float*)d_in[1];
    const float* ds_b   = (const float*)d_in[2];
    const float* g1_wih = (const float*)d_in[3];
    const float* g1_whh = (const float*)d_in[4];
    const float* g1_bih = (const float*)d_in[5];
    const float* g1_bhh = (const float*)d_in[6];
    const float* gr_wih = (const float*)d_in[7];
    const float* gr_whh = (const float*)d_in[8];
    const float* gr_bih = (const float*)d_in[9];
    const float* gr_bhh = (const float*)d_in[10];
    const float* gi_wih = (const float*)d_in[11];
    const float* gi_whh = (const float*)d_in[12];
    const float* gi_bih = (const float*)d_in[13];
    const float* gi_bhh = (const float*)d_in[14];
    const float* dr_w   = (const float*)d_in[15];
    const float* dr_b   = (const float*)d_in[16];
    const float* di_w   = (const float*)d_in[17];
    const float* di_b   = (const float*)d_in[18];

    float* out = (float*)d_out;
    float* ws  = (float*)d_ws;

    // workspace layout (float-element offsets)
    unsigned* wpk1 = (unsigned*)ws;
    unsigned* wpkr = wpk1 + WPK_ELEMS;
    unsigned* wpki = wpkr + WPK_ELEMS;
    float* xpA = ws + 3 * WPK_ELEMS;

    const size_t need_conc = (3 * WPK_ELEMS + 2 * XP_ELEMS + 3 * H_ELEMS) * sizeof(float);
    const bool conc = ws_size >= need_conc;

    float *xpB, *so, *sg, *r1, *i1;
    if (conc) {
        xpB = xpA + XP_ELEMS;
        so  = xpB + XP_ELEMS;
        sg  = so + H_ELEMS;
        i1  = sg + H_ELEMS;
        r1  = so;            // shared_out consumed before real_1 written
    } else {
        xpB = xpA;           // sequential reuse
        so  = xpA + XP_ELEMS;
        sg  = so + H_ELEMS;
        r1  = so;
        i1  = so;
    }

    const dim3 blk(256);
    const dim3 rblk(512);
    const dim3 gN256(NM / GEMM_BM, NH / GEMM_BN);                 // 250 x 4
    const dim3 gN768(NM / GEMM_BM, NG / GEMM_BN);                 // 250 x 12
    const dim3 gN513(NM / GEMM_BM, (NF + GEMM_BN - 1) / GEMM_BN); // 250 x 9
    const dim3 gPack((NG * NH / 2) / 256);                        // 384

    // pack recurrent weights to f16 (every call)
    pack_whh_f16<<<gPack, blk, 0, stream>>>(g1_whh, wpk1);
    pack_whh_f16<<<gPack, blk, 0, stream>>>(gr_whh, wpkr);
    pack_whh_f16<<<gPack, blk, 0, stream>>>(gi_whh, wpki);

    // shared dense: concat(x) [32000,1026] @ ds_w^T + ds_b -> so [32000,256]
    gemm_bias_kernel<true><<<gN256, blk, 0, stream>>>(x, ds_w, ds_b, so, NM, NH, 2 * NF);
    // xproj for GRU1
    gemm_bias_kernel<false><<<gN768, blk, 0, stream>>>(so, g1_wih, g1_bih, xpA, NM, NG, NH);
    // GRU1 recurrence -> sg
    gru_rec_kernel<<<dim3(NB), rblk, 0, stream>>>(
        xpA, wpk1, g1_bhh, sg, xpA, wpk1, g1_bhh, sg, NB);

    if (conc) {
        gemm_bias_kernel<false><<<gN768, blk, 0, stream>>>(sg, gr_wih, gr_bih, xpA, NM, NG, NH);
        gemm_bias_kernel<false><<<gN768, blk, 0, stream>>>(sg, gi_wih, gi_bih, xpB, NM, NG, NH);
        // real + imag recurrences concurrently (64 workgroups)
        gru_rec_kernel<<<dim3(2 * NB), rblk, 0, stream>>>(
            xpA, wpkr, gr_bhh, r1, xpB, wpki, gi_bhh, i1, NB);
        gemm_bias_kernel<false><<<gN513, blk, 0, stream>>>(r1, dr_w, dr_b, out, NM, NF, NH);
        gemm_bias_kernel<false><<<gN513, blk, 0, stream>>>(i1, di_w, di_b, out + OUT_HALF, NM, NF, NH);
    } else {
        gemm_bias_kernel<false><<<gN768, blk, 0, stream>>>(sg, gr_wih, gr_bih, xpA, NM, NG, NH);
        gru_rec_kernel<<<dim3(NB), rblk, 0, stream>>>(
            xpA, wpkr, gr_bhh, r1, xpA, wpkr, gr_bhh, r1, NB);
        gemm_bias_kernel<false><<<gN513, blk, 0, stream>>>(r1, dr_w, dr_b, out, NM, NF, NH);
        gemm_bias_kernel<false><<<gN768, blk, 0, stream>>>(sg, gi_wih, gi_bih, xpA, NM, NG, NH);
        gru_rec_kernel<<<dim3(NB), rblk, 0, stream>>>(
            xpA, wpki, gi_bhh, i1, xpA, wpki, gi_bhh, i1, NB);
        gemm_bias_kernel<false><<<gN513, blk, 0, stream>>>(i1, di_w, di_b, out + OUT_HALF, NM, NF, NH);
    }
}